// Round 6
// baseline (1361.552 us; speedup 1.0000x reference)
//
#include <hip/hip_runtime.h>
#include <math.h>

#define M_EDGES 50000
#define CHUNK 1024
#define NXCD 8

typedef unsigned int u32;
typedef unsigned short u16;

__device__ __forceinline__ float bflo(u32 u) { return __uint_as_float(u << 16); }
__device__ __forceinline__ float bfhi(u32 u) { return __uint_as_float(u & 0xffff0000u); }
__device__ __forceinline__ u32 packbf(float x, float y) {   // RNE both halves
  u32 a = __float_as_uint(x); a += 0x7fffu + ((a >> 16) & 1u);
  u32 b = __float_as_uint(y); b += 0x7fffu + ((b >> 16) & 1u);
  return (a >> 16) | (b & 0xffff0000u);
}
// xor swizzle at float4 granularity for GEMM W staging.
__device__ __forceinline__ int swz(int k) { return ((k >> 2) & 7) << 2; }

// ---------------- degree counting + rank capture ----------------
// The atomic's return value IS the pair's rank within its destination segment:
// stored coalesced here so fill_kernel needs no atomics at all.
__global__ void count_kernel(const int* __restrict__ pair_e, const int* __restrict__ pair_v,
                             int* __restrict__ cnt_e, int* __restrict__ cnt_v,
                             int* __restrict__ rank_e, int* __restrict__ rank_v, int P) {
  int p = blockIdx.x * blockDim.x + threadIdx.x;
  if (p >= P) return;
  rank_e[p] = atomicAdd(&cnt_e[pair_e[p]], 1);
  rank_v[p] = atomicAdd(&cnt_v[pair_v[p]], 1);
}

// ---------------- hierarchical scan, phase A: per-chunk totals ----------------
__global__ __launch_bounds__(1024) void blocksum_kernel(
    const int* __restrict__ cnt_e, const int* __restrict__ cnt_v,
    int* __restrict__ part, int CE, int M, int N) {
  const int b = blockIdx.x;
  const int* cnt;
  int n, chunk;
  if (b < CE) { cnt = cnt_e; n = M; chunk = b; }
  else        { cnt = cnt_v; n = N; chunk = b - CE; }
  const int i = chunk * CHUNK + (int)threadIdx.x;
  int x = (i < n) ? cnt[i] : 0;
#pragma unroll
  for (int m = 32; m >= 1; m >>= 1) x += __shfl_xor(x, m, 64);
  __shared__ int ws[16];
  if ((threadIdx.x & 63) == 0) ws[threadIdx.x >> 6] = x;
  __syncthreads();
  if (threadIdx.x == 0) {
    int t = 0;
#pragma unroll
    for (int q = 0; q < 16; ++q) t += ws[q];
    part[b] = t;
  }
}

// ---------------- phase B: exclusive-scan chunk totals (1 block) ----------------
__global__ __launch_bounds__(256) void partscan_kernel(
    int* __restrict__ part, int CE, int CV,
    int* __restrict__ off_e, int* __restrict__ off_v, int M, int N) {
  __shared__ int sh[256];
  const int tid = (int)threadIdx.x;
  for (int s = 0; s < 2; ++s) {
    const int base = s ? CE : 0;
    const int count = s ? CV : CE;   // both <= 256
    int x = (tid < count) ? part[base + tid] : 0;
    sh[tid] = x;
    __syncthreads();
    for (int ofs = 1; ofs < 256; ofs <<= 1) {
      int v = (tid >= ofs) ? sh[tid - ofs] : 0;
      __syncthreads();
      sh[tid] += v;
      __syncthreads();
    }
    if (tid < count) part[base + tid] = sh[tid] - x;   // exclusive
    if (tid == 0) {
      const int tot = sh[count - 1];
      if (s == 0) off_e[M] = tot; else off_v[N] = tot;
    }
    __syncthreads();
  }
}

// ---------------- phase C: local scan + offsets + inv-degrees ----------------
__global__ __launch_bounds__(1024) void blockscan_kernel(
    const int* __restrict__ cnt_e, const int* __restrict__ cnt_v,
    const int* __restrict__ part,
    int* __restrict__ off_e, int* __restrict__ off_v,
    float* __restrict__ de_inv, float* __restrict__ dv_inv, float* __restrict__ dv_isqrt,
    int CE, int M, int N) {
  __shared__ int sh[CHUNK];
  const int b = blockIdx.x;
  const int tid = (int)threadIdx.x;
  const int* cnt;
  int n, chunk;
  int* off;
  float *i1, *i2;
  if (b < CE) { cnt = cnt_e; n = M; chunk = b;      off = off_e; i1 = de_inv; i2 = nullptr; }
  else        { cnt = cnt_v; n = N; chunk = b - CE; off = off_v; i1 = dv_inv; i2 = dv_isqrt; }
  const int i = chunk * CHUNK + tid;
  const int x = (i < n) ? cnt[i] : 0;
  sh[tid] = x;
  __syncthreads();
  for (int ofs = 1; ofs < CHUNK; ofs <<= 1) {
    int v = (tid >= ofs) ? sh[tid - ofs] : 0;
    __syncthreads();
    sh[tid] += v;
    __syncthreads();
  }
  if (i < n) {
    off[i] = part[b] + sh[tid] - x;
    const float m = (float)(x > 1 ? x : 1);
    i1[i] = 1.0f / m;
    if (i2) i2[i] = 1.0f / sqrtf(m);
  }
}

// ---------------- GEMM: H = X@W^T + b; fused s=H.w_src, d=H.w_dst ----------------
// stores Hs = H * dv_isqrt[row] as packed bf16 (H only feeds P1, which needs that scale).
__global__ __launch_bounds__(256) void gemm_kernel(
    const float* __restrict__ X, const float* __restrict__ W,
    const float* __restrict__ bias, const float* __restrict__ wsrc,
    const float* __restrict__ wdst, const float* __restrict__ dv_isqrt,
    u16* __restrict__ Hb, float* __restrict__ s_out, float* __restrict__ d_out,
    int N) {
  __shared__ float lw[64 * 128];   // lw[kk*128 + (c ^ swz(kk))] = W[c][half*64+kk]
  __shared__ float lx[32 * 128];   // lx[r*128 + k]
  const int tid = threadIdx.x;
  const int row0 = blockIdx.x * 32;

  for (int g = tid; g < 32 * 32; g += 256) {
    const int r = g >> 5;
    const int k4 = (g & 31) << 2;
    int rr = row0 + r;
    if (rr >= N) rr = N - 1;
    *(float4*)(lx + r * 128 + k4) = *(const float4*)(X + (size_t)rr * 128 + k4);
  }

  const int tx = tid & 31;
  const int ty = tid >> 5;
  const int c0 = tx << 2;
  const int r0 = ty << 2;
  float acc[4][4] = {};

  for (int half = 0; half < 2; ++half) {
    __syncthreads();
    for (int g = tid; g < 128 * 16; g += 256) {
      const int c = g >> 4;
      const int kk4 = (g & 15) << 2;
      const float4 v = *(const float4*)(W + (size_t)c * 128 + half * 64 + kk4);
      const int s = swz(kk4);
      lw[(kk4 + 0) * 128 + (c ^ s)] = v.x;
      lw[(kk4 + 1) * 128 + (c ^ s)] = v.y;
      lw[(kk4 + 2) * 128 + (c ^ s)] = v.z;
      lw[(kk4 + 3) * 128 + (c ^ s)] = v.w;
    }
    __syncthreads();
#pragma unroll 8
    for (int kk = 0; kk < 64; ++kk) {
      const int k = half * 64 + kk;
      const float4 wv = *(const float4*)(lw + kk * 128 + (c0 ^ swz(kk)));
      const float x0 = lx[(r0 + 0) * 128 + k];
      const float x1 = lx[(r0 + 1) * 128 + k];
      const float x2 = lx[(r0 + 2) * 128 + k];
      const float x3 = lx[(r0 + 3) * 128 + k];
      acc[0][0] += x0 * wv.x; acc[0][1] += x0 * wv.y; acc[0][2] += x0 * wv.z; acc[0][3] += x0 * wv.w;
      acc[1][0] += x1 * wv.x; acc[1][1] += x1 * wv.y; acc[1][2] += x1 * wv.z; acc[1][3] += x1 * wv.w;
      acc[2][0] += x2 * wv.x; acc[2][1] += x2 * wv.y; acc[2][2] += x2 * wv.z; acc[2][3] += x2 * wv.w;
      acc[3][0] += x3 * wv.x; acc[3][1] += x3 * wv.y; acc[3][2] += x3 * wv.z; acc[3][3] += x3 * wv.w;
    }
  }

  const float4 bv = *(const float4*)(bias + c0);
  const float4 sv = *(const float4*)(wsrc + c0);
  const float4 dv = *(const float4*)(wdst + c0);

#pragma unroll
  for (int r = 0; r < 4; ++r) {
    const int row = row0 + r0 + r;
    float4 h;
    h.x = acc[r][0] + bv.x; h.y = acc[r][1] + bv.y;
    h.z = acc[r][2] + bv.z; h.w = acc[r][3] + bv.w;
    float ps = h.x * sv.x + h.y * sv.y + h.z * sv.z + h.w * sv.w;
    float pd = h.x * dv.x + h.y * dv.y + h.z * dv.z + h.w * dv.w;
#pragma unroll
    for (int m = 16; m >= 1; m >>= 1) {
      ps += __shfl_xor(ps, m, 64);
      pd += __shfl_xor(pd, m, 64);
    }
    if (row < N) {
      const float sc = dv_isqrt[row];
      uint2 pk;
      pk.x = packbf(h.x * sc, h.y * sc);
      pk.y = packbf(h.z * sc, h.w * sc);
      *(uint2*)(Hb + (size_t)row * 128 + c0) = pk;
      if (tx == 0) { s_out[row] = ps; d_out[row] = pd; }
    }
  }
}

// ---------------- XCD-partitioned atomic-free CSR fill + attention weight ----------------
// XCD k commits only destinations in its 1/8 range so scatter lines accumulate in one
// L2 and write back once; pair/rank streams are non-temporal so they can't evict the
// scatter window. Slot = off[dest] + precomputed rank (no atomics).
// es = exp(clip(leaky_relu(s[src]+d[v], 0.2), 0.001, 5)); clip bounds exp<=148.4 so
// softmax needs no max-subtraction (analytically identical).
__global__ __launch_bounds__(256) void fill_kernel(
    const int* __restrict__ pair_e, const int* __restrict__ pair_v,
    const int* __restrict__ src_v,
    const int* __restrict__ rank_e, const int* __restrict__ rank_v,
    const int* __restrict__ edge_off, const int* __restrict__ vtx_off,
    int* __restrict__ edge_vtx, int* __restrict__ vtx_edge, float* __restrict__ vtx_score,
    const float* __restrict__ svec, const float* __restrict__ dvec,
    int P, int bpx, int M, int N) {
  const int xcd = blockIdx.x & (NXCD - 1);
  const int ord = blockIdx.x >> 3;
  const int per = (P + bpx - 1) / bpx;
  const int lo = ord * per;
  const int hi = min(lo + per, P);
  const int e_lo = (int)((long long)M * xcd / NXCD);
  const int e_hi = (int)((long long)M * (xcd + 1) / NXCD);
  const int v_lo = (int)((long long)N * xcd / NXCD);
  const int v_hi = (int)((long long)N * (xcd + 1) / NXCD);
  for (int p = lo + (int)threadIdx.x; p < hi; p += 256) {
    const int e = __builtin_nontemporal_load(pair_e + p);
    const int v = __builtin_nontemporal_load(pair_v + p);
    if (e >= e_lo && e < e_hi) {
      const int ie = edge_off[e] + __builtin_nontemporal_load(rank_e + p);
      edge_vtx[ie] = v;
    }
    if (v >= v_lo && v < v_hi) {
      const int iv = vtx_off[v] + __builtin_nontemporal_load(rank_v + p);
      vtx_edge[iv] = e;
      float sc = svec[__builtin_nontemporal_load(src_v + p)] + dvec[v];
      sc = sc > 0.f ? sc : 0.2f * sc;           // leaky_relu(0.2)
      sc = fminf(fmaxf(sc, 0.001f), 5.0f);      // clip
      vtx_score[iv] = __expf(sc);
    }
  }
}

#define ACC8(r, p)                                         \
  a[0] += bflo((r).x) * (p); a[1] += bfhi((r).x) * (p);    \
  a[2] += bflo((r).y) * (p); a[3] += bfhi((r).y) * (p);    \
  a[4] += bflo((r).z) * (p); a[5] += bfhi((r).z) * (p);    \
  a[6] += bflo((r).w) * (p); a[7] += bfhi((r).w) * (p);

// ---------------- channel-split segment gather-reduce ----------------
// class = blockIdx&7 (XCD round-robin). Class owns one 64B line-group g=class&3
// (bf16 cols [g*32,g*32+32)) and one segment half h=class>>2 -> per-XCD source
// slice = rows*64B, L2-resident, so the P gathers hit local L2 instead of L3.
// Wave per segment: 16 entries/iter x 4 lanes x 16B. lst is NT-streamed.
__global__ __launch_bounds__(256) void seg_pass_kernel(
    const u16* __restrict__ src, void* __restrict__ dst,
    const int* __restrict__ off, const int* __restrict__ lst,
    const float* __restrict__ post_scale,
    int nseg, int final_mode) {
  const int cls = blockIdx.x & 7;
  const int ord = blockIdx.x >> 3;
  const int g = cls & 3;           // 64B line-group
  const int h = cls >> 2;          // segment half
  const int halfseg = (nseg + 1) >> 1;
  const int lo = h ? halfseg : 0;
  const int hi = h ? nseg : halfseg;
  const int seg = lo + ord * 4 + ((int)threadIdx.x >> 6);
  if (seg >= hi) return;
  const int lane = (int)threadIdx.x & 63;
  const int eg = lane >> 2;        // entry group 0..15
  const int cl = lane & 3;         // 16B sub-slice 0..3
  const int coff = g * 32 + cl * 8;
  const int beg = off[seg], end = off[seg + 1];
  float a[8] = {};
  int i = beg;
  for (; i + 16 <= end; i += 16) {
    const int j = __builtin_nontemporal_load(lst + i + eg);
    const uint4 r = *(const uint4*)(src + (size_t)j * 128 + coff);
    ACC8(r, 1.0f)
  }
  if (i + eg < end) {
    const int j = __builtin_nontemporal_load(lst + i + eg);
    const uint4 r = *(const uint4*)(src + (size_t)j * 128 + coff);
    ACC8(r, 1.0f)
  }
#pragma unroll
  for (int k = 0; k < 8; ++k) {
    a[k] += __shfl_xor(a[k], 4, 64);
    a[k] += __shfl_xor(a[k], 8, 64);
    a[k] += __shfl_xor(a[k], 16, 64);
    a[k] += __shfl_xor(a[k], 32, 64);
  }
  if (eg != 0) return;
  const float ps = post_scale ? post_scale[seg] : 1.0f;
#pragma unroll
  for (int k = 0; k < 8; ++k) a[k] *= ps;
  if (final_mode) {
#pragma unroll
    for (int k = 0; k < 8; ++k) a[k] = a[k] > 0.f ? a[k] : expm1f(a[k]);
    float* o = (float*)dst + (size_t)seg * 128 + g * 32 + cl * 8;
    *(float4*)(o + 0) = make_float4(a[0], a[1], a[2], a[3]);
    *(float4*)(o + 4) = make_float4(a[4], a[5], a[6], a[7]);
  } else {
    uint4 pk;
    pk.x = packbf(a[0], a[1]); pk.y = packbf(a[2], a[3]);
    pk.z = packbf(a[4], a[5]); pk.w = packbf(a[6], a[7]);
    *(uint4*)((u16*)dst + (size_t)seg * 128 + coff) = pk;
  }
}

// ---------------- attention e2v, channel-split: Xv1[v] = sum es*Xe1[e] / sum es ----------------
__global__ __launch_bounds__(256) void attn_pass_kernel(
    const u16* __restrict__ src, u16* __restrict__ dst,
    const int* __restrict__ off, const int* __restrict__ lst,
    const float* __restrict__ score, int nseg) {
  const int cls = blockIdx.x & 7;
  const int ord = blockIdx.x >> 3;
  const int g = cls & 3;
  const int h = cls >> 2;
  const int halfseg = (nseg + 1) >> 1;
  const int lo = h ? halfseg : 0;
  const int hi = h ? nseg : halfseg;
  const int seg = lo + ord * 4 + ((int)threadIdx.x >> 6);
  if (seg >= hi) return;
  const int lane = (int)threadIdx.x & 63;
  const int eg = lane >> 2;
  const int cl = lane & 3;
  const int coff = g * 32 + cl * 8;
  const int beg = off[seg], end = off[seg + 1];
  float a[8] = {};
  float den = 0.f;
  int i = beg;
  for (; i + 16 <= end; i += 16) {
    const int j = __builtin_nontemporal_load(lst + i + eg);
    const float es = __builtin_nontemporal_load(score + i + eg);
    const uint4 r = *(const uint4*)(src + (size_t)j * 128 + coff);
    ACC8(r, es)
    den += es;
  }
  if (i + eg < end) {
    const int j = __builtin_nontemporal_load(lst + i + eg);
    const float es = __builtin_nontemporal_load(score + i + eg);
    const uint4 r = *(const uint4*)(src + (size_t)j * 128 + coff);
    ACC8(r, es)
    den += es;
  }
#pragma unroll
  for (int k = 0; k < 8; ++k) {
    a[k] += __shfl_xor(a[k], 4, 64);
    a[k] += __shfl_xor(a[k], 8, 64);
    a[k] += __shfl_xor(a[k], 16, 64);
    a[k] += __shfl_xor(a[k], 32, 64);
  }
  den += __shfl_xor(den, 4, 64);
  den += __shfl_xor(den, 8, 64);
  den += __shfl_xor(den, 16, 64);
  den += __shfl_xor(den, 32, 64);
  if (eg != 0) return;
  const float inv = (end > beg) ? 1.0f / den : 0.0f;
  uint4 pk;
  pk.x = packbf(a[0] * inv, a[1] * inv); pk.y = packbf(a[2] * inv, a[3] * inv);
  pk.z = packbf(a[4] * inv, a[5] * inv); pk.w = packbf(a[6] * inv, a[7] * inv);
  *(uint4*)(dst + (size_t)seg * 128 + coff) = pk;
}

extern "C" void kernel_launch(void* const* d_in, const int* in_sizes, int n_in,
                              void* d_out, int out_size, void* d_ws, size_t ws_size,
                              hipStream_t stream) {
  const float* X      = (const float*)d_in[0];
  const int*   pair_v = (const int*)d_in[1];
  const int*   pair_e = (const int*)d_in[2];
  const int*   src_v  = (const int*)d_in[3];
  const float* W      = (const float*)d_in[4];
  const float* bias   = (const float*)d_in[5];
  const float* wsrc   = (const float*)d_in[6];
  const float* wdst   = (const float*)d_in[7];

  const int N = in_sizes[0] / 128;
  const int P = in_sizes[1];
  const int M = M_EDGES;   // fixed by problem definition (pair_e in [0, 50000))
  const int CE = (M + CHUNK - 1) / CHUNK;   // <=256 for partscan
  const int CV = (N + CHUNK - 1) / CHUNK;   // <=256 for partscan

  char* w = (char*)d_ws;
  auto alloc = [&](size_t bytes) -> char* {
    char* p = w;
    w += (bytes + 255) & ~(size_t)255;
    return p;
  };
  // ---- zero-initialized region (one memset: counts only) ----
  char* zbase = w;
  int* cnt_e = (int*)alloc((size_t)M * 4);
  int* cnt_v = (int*)alloc((size_t)N * 4);
  const size_t zbytes = (size_t)(w - zbase);
  // ---- rest of workspace ----
  int*   part      = (int*)alloc((size_t)(CE + CV) * 4);
  int*   edge_off  = (int*)alloc((size_t)(M + 1) * 4);
  int*   vtx_off   = (int*)alloc((size_t)(N + 1) * 4);
  float* de_inv    = (float*)alloc((size_t)M * 4);
  float* dv_inv    = (float*)alloc((size_t)N * 4);
  float* dv_isqrt  = (float*)alloc((size_t)N * 4);
  float* svec      = (float*)alloc((size_t)N * 4);
  float* dvec      = (float*)alloc((size_t)N * 4);
  int*   rank_e    = (int*)alloc((size_t)P * 4);
  int*   rank_v    = (int*)alloc((size_t)P * 4);
  int*   edge_vtx  = (int*)alloc((size_t)P * 4);
  int*   vtx_edge  = (int*)alloc((size_t)P * 4);
  float* vtx_score = (float*)alloc((size_t)P * 4);
  u16*   bufN      = (u16*)alloc((size_t)N * 128 * 2);  // Hs -> Hs2 -> Xv1 (bf16)
  u16*   bufM      = (u16*)alloc((size_t)M * 128 * 2);  // Xe -> Xe1 -> Xe2 (bf16)

  hipMemsetAsync(zbase, 0, zbytes, stream);

  const int pb = (P + 255) / 256;
  count_kernel<<<pb, 256, 0, stream>>>(pair_e, pair_v, cnt_e, cnt_v, rank_e, rank_v, P);
  blocksum_kernel<<<CE + CV, 1024, 0, stream>>>(cnt_e, cnt_v, part, CE, M, N);
  partscan_kernel<<<1, 256, 0, stream>>>(part, CE, CV, edge_off, vtx_off, M, N);
  blockscan_kernel<<<CE + CV, 1024, 0, stream>>>(cnt_e, cnt_v, part, edge_off, vtx_off,
                                                 de_inv, dv_inv, dv_isqrt, CE, M, N);
  gemm_kernel<<<(N + 31) / 32, 256, 0, stream>>>(X, W, bias, wsrc, wdst, dv_isqrt,
                                                 bufN, svec, dvec, N);
  const int bpx = 128;
  fill_kernel<<<bpx * NXCD, 256, 0, stream>>>(pair_e, pair_v, src_v, rank_e, rank_v,
                                              edge_off, vtx_off,
                                              edge_vtx, vtx_edge, vtx_score,
                                              svec, dvec, P, bpx, M, N);

  // grids: 8 classes x ceil(half/4) blocks, 4 segments (waves) per block
  const int gm = 8 * (((M + 1) / 2 + 3) / 4);
  const int gn = 8 * (((N + 1) / 2 + 3) / 4);
  // P1: Xe  = de_inv * sum Hs[v]          (dv_isqrt folded into Hs at GEMM)
  seg_pass_kernel<<<gm, 256, 0, stream>>>(bufN, bufM, edge_off, edge_vtx, de_inv, M, 0);
  // P2: Hs2 = dv_isqrt * sum Xe[e]
  seg_pass_kernel<<<gn, 256, 0, stream>>>(bufM, bufN, vtx_off, vtx_edge, dv_isqrt, N, 0);
  // P3: Xe1 = de_inv * sum Hs2[v]
  seg_pass_kernel<<<gm, 256, 0, stream>>>(bufN, bufM, edge_off, edge_vtx, de_inv, M, 0);
  // P4: Xv1 = softmax-weighted sum of Xe1[e]
  attn_pass_kernel<<<gn, 256, 0, stream>>>(bufM, bufN, vtx_off, vtx_edge, vtx_score, N);
  // P5: Xe2 = de_inv * sum Xv1[v]
  seg_pass_kernel<<<gm, 256, 0, stream>>>(bufN, bufM, edge_off, edge_vtx, de_inv, M, 0);
  // P6: out = elu(dv_inv * sum Xe2[e])  -> fp32
  seg_pass_kernel<<<gn, 256, 0, stream>>>(bufM, d_out, vtx_off, vtx_edge, dv_inv, N, 1);
}

// Round 7
// 791.498 us; speedup vs baseline: 1.7202x; 1.7202x over previous
//
#include <hip/hip_runtime.h>
#include <math.h>

#define M_EDGES 50000
#define CHUNK 1024

typedef unsigned int u32;
typedef unsigned short u16;

__device__ __forceinline__ float bflo(u32 u) { return __uint_as_float(u << 16); }
__device__ __forceinline__ float bfhi(u32 u) { return __uint_as_float(u & 0xffff0000u); }
__device__ __forceinline__ u32 packbf(float x, float y) {   // RNE both halves
  u32 a = __float_as_uint(x); a += 0x7fffu + ((a >> 16) & 1u);
  u32 b = __float_as_uint(y); b += 0x7fffu + ((b >> 16) & 1u);
  return (a >> 16) | (b & 0xffff0000u);
}
// xor swizzle at float4 granularity for GEMM W staging.
__device__ __forceinline__ int swz(int k) { return ((k >> 2) & 7) << 2; }

// ---------------- degree counting ----------------
__global__ void count_kernel(const int* __restrict__ pair_e, const int* __restrict__ pair_v,
                             int* __restrict__ cnt_e, int* __restrict__ cnt_v, int P) {
  int p = blockIdx.x * blockDim.x + threadIdx.x;
  if (p >= P) return;
  atomicAdd(&cnt_e[pair_e[p]], 1);
  atomicAdd(&cnt_v[pair_v[p]], 1);
}

// ---------------- hierarchical scan, phase A: per-chunk totals ----------------
__global__ __launch_bounds__(1024) void blocksum_kernel(
    const int* __restrict__ cnt_e, const int* __restrict__ cnt_v,
    int* __restrict__ part, int CE, int M, int N) {
  const int b = blockIdx.x;
  const int* cnt;
  int n, chunk;
  if (b < CE) { cnt = cnt_e; n = M; chunk = b; }
  else        { cnt = cnt_v; n = N; chunk = b - CE; }
  const int i = chunk * CHUNK + (int)threadIdx.x;
  int x = (i < n) ? cnt[i] : 0;
#pragma unroll
  for (int m = 32; m >= 1; m >>= 1) x += __shfl_xor(x, m, 64);
  __shared__ int ws[16];
  if ((threadIdx.x & 63) == 0) ws[threadIdx.x >> 6] = x;
  __syncthreads();
  if (threadIdx.x == 0) {
    int t = 0;
#pragma unroll
    for (int q = 0; q < 16; ++q) t += ws[q];
    part[b] = t;
  }
}

// ---------------- phase B: exclusive-scan chunk totals (1 block) ----------------
__global__ __launch_bounds__(256) void partscan_kernel(
    int* __restrict__ part, int CE, int CV,
    int* __restrict__ off_e, int* __restrict__ off_v, int M, int N) {
  __shared__ int sh[256];
  const int tid = (int)threadIdx.x;
  for (int s = 0; s < 2; ++s) {
    const int base = s ? CE : 0;
    const int count = s ? CV : CE;   // both <= 256
    int x = (tid < count) ? part[base + tid] : 0;
    sh[tid] = x;
    __syncthreads();
    for (int ofs = 1; ofs < 256; ofs <<= 1) {
      int v = (tid >= ofs) ? sh[tid - ofs] : 0;
      __syncthreads();
      sh[tid] += v;
      __syncthreads();
    }
    if (tid < count) part[base + tid] = sh[tid] - x;   // exclusive
    if (tid == 0) {
      const int tot = sh[count - 1];
      if (s == 0) off_e[M] = tot; else off_v[N] = tot;
    }
    __syncthreads();
  }
}

// ---------------- phase C: local scan + offsets + cursors + inv-degrees ----------------
__global__ __launch_bounds__(1024) void blockscan_kernel(
    const int* __restrict__ cnt_e, const int* __restrict__ cnt_v,
    const int* __restrict__ part,
    int* __restrict__ off_e, int* __restrict__ off_v,
    int* __restrict__ cur_e, int* __restrict__ cur_v,
    float* __restrict__ de_inv, float* __restrict__ dv_inv, float* __restrict__ dv_isqrt,
    int CE, int M, int N) {
  __shared__ int sh[CHUNK];
  const int b = blockIdx.x;
  const int tid = (int)threadIdx.x;
  const int* cnt;
  int n, chunk;
  int *off, *cur;
  float *i1, *i2;
  if (b < CE) { cnt = cnt_e; n = M; chunk = b;      off = off_e; cur = cur_e; i1 = de_inv; i2 = nullptr; }
  else        { cnt = cnt_v; n = N; chunk = b - CE; off = off_v; cur = cur_v; i1 = dv_inv; i2 = dv_isqrt; }
  const int i = chunk * CHUNK + tid;
  const int x = (i < n) ? cnt[i] : 0;
  sh[tid] = x;
  __syncthreads();
  for (int ofs = 1; ofs < CHUNK; ofs <<= 1) {
    int v = (tid >= ofs) ? sh[tid - ofs] : 0;
    __syncthreads();
    sh[tid] += v;
    __syncthreads();
  }
  if (i < n) {
    const int o = part[b] + sh[tid] - x;
    off[i] = o;
    cur[i] = o;              // cursor pre-initialized to offset
    const float m = (float)(x > 1 ? x : 1);
    i1[i] = 1.0f / m;
    if (i2) i2[i] = 1.0f / sqrtf(m);
  }
}

// ---------------- GEMM: H = X@W^T + b; fused s=H.w_src, d=H.w_dst ----------------
// stores Hs = H * dv_isqrt[row] as packed bf16 (H only feeds P1, which needs that scale).
__global__ __launch_bounds__(256) void gemm_kernel(
    const float* __restrict__ X, const float* __restrict__ W,
    const float* __restrict__ bias, const float* __restrict__ wsrc,
    const float* __restrict__ wdst, const float* __restrict__ dv_isqrt,
    u16* __restrict__ Hb, float* __restrict__ s_out, float* __restrict__ d_out,
    int N) {
  __shared__ float lw[64 * 128];   // lw[kk*128 + (c ^ swz(kk))] = W[c][half*64+kk]
  __shared__ float lx[32 * 128];   // lx[r*128 + k]
  const int tid = threadIdx.x;
  const int row0 = blockIdx.x * 32;

  for (int g = tid; g < 32 * 32; g += 256) {
    const int r = g >> 5;
    const int k4 = (g & 31) << 2;
    int rr = row0 + r;
    if (rr >= N) rr = N - 1;
    *(float4*)(lx + r * 128 + k4) = *(const float4*)(X + (size_t)rr * 128 + k4);
  }

  const int tx = tid & 31;
  const int ty = tid >> 5;
  const int c0 = tx << 2;
  const int r0 = ty << 2;
  float acc[4][4] = {};

  for (int half = 0; half < 2; ++half) {
    __syncthreads();
    for (int g = tid; g < 128 * 16; g += 256) {
      const int c = g >> 4;
      const int kk4 = (g & 15) << 2;
      const float4 v = *(const float4*)(W + (size_t)c * 128 + half * 64 + kk4);
      const int s = swz(kk4);
      lw[(kk4 + 0) * 128 + (c ^ s)] = v.x;
      lw[(kk4 + 1) * 128 + (c ^ s)] = v.y;
      lw[(kk4 + 2) * 128 + (c ^ s)] = v.z;
      lw[(kk4 + 3) * 128 + (c ^ s)] = v.w;
    }
    __syncthreads();
#pragma unroll 8
    for (int kk = 0; kk < 64; ++kk) {
      const int k = half * 64 + kk;
      const float4 wv = *(const float4*)(lw + kk * 128 + (c0 ^ swz(kk)));
      const float x0 = lx[(r0 + 0) * 128 + k];
      const float x1 = lx[(r0 + 1) * 128 + k];
      const float x2 = lx[(r0 + 2) * 128 + k];
      const float x3 = lx[(r0 + 3) * 128 + k];
      acc[0][0] += x0 * wv.x; acc[0][1] += x0 * wv.y; acc[0][2] += x0 * wv.z; acc[0][3] += x0 * wv.w;
      acc[1][0] += x1 * wv.x; acc[1][1] += x1 * wv.y; acc[1][2] += x1 * wv.z; acc[1][3] += x1 * wv.w;
      acc[2][0] += x2 * wv.x; acc[2][1] += x2 * wv.y; acc[2][2] += x2 * wv.z; acc[2][3] += x2 * wv.w;
      acc[3][0] += x3 * wv.x; acc[3][1] += x3 * wv.y; acc[3][2] += x3 * wv.z; acc[3][3] += x3 * wv.w;
    }
  }

  const float4 bv = *(const float4*)(bias + c0);
  const float4 sv = *(const float4*)(wsrc + c0);
  const float4 dv = *(const float4*)(wdst + c0);

#pragma unroll
  for (int r = 0; r < 4; ++r) {
    const int row = row0 + r0 + r;
    float4 h;
    h.x = acc[r][0] + bv.x; h.y = acc[r][1] + bv.y;
    h.z = acc[r][2] + bv.z; h.w = acc[r][3] + bv.w;
    float ps = h.x * sv.x + h.y * sv.y + h.z * sv.z + h.w * sv.w;
    float pd = h.x * dv.x + h.y * dv.y + h.z * dv.z + h.w * dv.w;
#pragma unroll
    for (int m = 16; m >= 1; m >>= 1) {
      ps += __shfl_xor(ps, m, 64);
      pd += __shfl_xor(pd, m, 64);
    }
    if (row < N) {
      const float sc = dv_isqrt[row];
      uint2 pk;
      pk.x = packbf(h.x * sc, h.y * sc);
      pk.y = packbf(h.z * sc, h.w * sc);
      *(uint2*)(Hb + (size_t)row * 128 + c0) = pk;
      if (tx == 0) { s_out[row] = ps; d_out[row] = pd; }
    }
  }
}

// ---------------- CSR fill + per-slot attention weight ----------------
// es = exp(clip(leaky_relu(s[src]+d[v], 0.2), 0.001, 5)); clip bounds exp<=148.4 so
// softmax needs no max-subtraction (analytically identical). (e,es) packed in one int2.
__global__ void fill_kernel(const int* __restrict__ pair_e, const int* __restrict__ pair_v,
                            const int* __restrict__ src_v,
                            int* __restrict__ cur_e, int* __restrict__ cur_v,
                            int* __restrict__ edge_vtx, int2* __restrict__ vtx_es,
                            const float* __restrict__ svec, const float* __restrict__ dvec,
                            int P) {
  int p = blockIdx.x * blockDim.x + threadIdx.x;
  if (p >= P) return;
  int e = pair_e[p], v = pair_v[p];
  int ie = atomicAdd(&cur_e[e], 1);
  edge_vtx[ie] = v;
  int iv = atomicAdd(&cur_v[v], 1);
  float sc = svec[src_v[p]] + dvec[v];
  sc = sc > 0.f ? sc : 0.2f * sc;           // leaky_relu(0.2)
  sc = fminf(fmaxf(sc, 0.001f), 5.0f);      // clip
  vtx_es[iv] = make_int2(e, __float_as_int(__expf(sc)));
}

#define ACC8(r, p)                                         \
  a[0] += bflo((r).x) * (p); a[1] += bfhi((r).x) * (p);    \
  a[2] += bflo((r).y) * (p); a[3] += bfhi((r).y) * (p);    \
  a[4] += bflo((r).z) * (p); a[5] += bfhi((r).z) * (p);    \
  a[6] += bflo((r).w) * (p); a[7] += bfhi((r).w) * (p);

// ---------------- segment gather-reduce, quarter-wave, 16 entries in flight ----------------
// wave = segment; quarter q owns entries {i+q, i+4+q, i+8+q, i+12+q} per iter (4x MLP
// vs single-batch: the passes are L3-latency-bound at ~7.6 B/cy/CU, nowhere near BW).
// 16 lanes x uint4 (8 bf16 ch) = 256B row. ls = ints per list entry (2 for int2 lists).
// dst[seg] = post[seg] * sum_i src[lst[i]].  final_mode: ELU + fp32 output.
__global__ __launch_bounds__(256) void seg_pass_kernel(
    const u16* __restrict__ src, void* __restrict__ dst,
    const int* __restrict__ off, const int* __restrict__ lst, int ls,
    const float* __restrict__ post_scale,
    int nseg, int final_mode) {
  const int seg = blockIdx.x * 4 + ((int)threadIdx.x >> 6);
  if (seg >= nseg) return;
  const int lane = (int)threadIdx.x & 63;
  const int q = lane >> 4;
  const int cl = lane & 15;
  const int beg = off[seg], end = off[seg + 1];
  float a[8] = {};
  int i = beg;
  for (; i + 16 <= end; i += 16) {
    const int j0 = lst[(size_t)(i + q) * ls];
    const int j1 = lst[(size_t)(i + 4 + q) * ls];
    const int j2 = lst[(size_t)(i + 8 + q) * ls];
    const int j3 = lst[(size_t)(i + 12 + q) * ls];
    const uint4 r0 = *(const uint4*)(src + (size_t)j0 * 128 + cl * 8);
    const uint4 r1 = *(const uint4*)(src + (size_t)j1 * 128 + cl * 8);
    const uint4 r2 = *(const uint4*)(src + (size_t)j2 * 128 + cl * 8);
    const uint4 r3 = *(const uint4*)(src + (size_t)j3 * 128 + cl * 8);
    ACC8(r0, 1.0f) ACC8(r1, 1.0f) ACC8(r2, 1.0f) ACC8(r3, 1.0f)
  }
  if (i + 8 <= end) {
    const int j0 = lst[(size_t)(i + q) * ls];
    const int j1 = lst[(size_t)(i + 4 + q) * ls];
    const uint4 r0 = *(const uint4*)(src + (size_t)j0 * 128 + cl * 8);
    const uint4 r1 = *(const uint4*)(src + (size_t)j1 * 128 + cl * 8);
    ACC8(r0, 1.0f) ACC8(r1, 1.0f)
    i += 8;
  }
  if (i + 4 <= end) {
    const int j0 = lst[(size_t)(i + q) * ls];
    const uint4 r0 = *(const uint4*)(src + (size_t)j0 * 128 + cl * 8);
    ACC8(r0, 1.0f)
    i += 4;
  }
  if (i + q < end) {
    const int j0 = lst[(size_t)(i + q) * ls];
    const uint4 r0 = *(const uint4*)(src + (size_t)j0 * 128 + cl * 8);
    ACC8(r0, 1.0f)
  }
#pragma unroll
  for (int k = 0; k < 8; ++k) {
    a[k] += __shfl_xor(a[k], 16, 64);
    a[k] += __shfl_xor(a[k], 32, 64);
  }
  if (q != 0) return;
  const float ps = post_scale ? post_scale[seg] : 1.0f;
#pragma unroll
  for (int k = 0; k < 8; ++k) a[k] *= ps;
  if (final_mode) {
#pragma unroll
    for (int k = 0; k < 8; ++k) a[k] = a[k] > 0.f ? a[k] : expm1f(a[k]);
    float* o = (float*)dst + (size_t)seg * 128 + cl * 8;
    *(float4*)(o + 0) = make_float4(a[0], a[1], a[2], a[3]);
    *(float4*)(o + 4) = make_float4(a[4], a[5], a[6], a[7]);
  } else {
    uint4 pk;
    pk.x = packbf(a[0], a[1]); pk.y = packbf(a[2], a[3]);
    pk.z = packbf(a[4], a[5]); pk.w = packbf(a[6], a[7]);
    *(uint4*)((u16*)dst + (size_t)seg * 128 + cl * 8) = pk;
  }
}

// ---------------- attention e2v: Xv1[v] = sum es_i*Xe1[e_i] / sum es_i ----------------
__global__ __launch_bounds__(256) void attn_pass_kernel(
    const u16* __restrict__ src, u16* __restrict__ dst,
    const int* __restrict__ off, const int2* __restrict__ lst_es, int nseg) {
  const int seg = blockIdx.x * 4 + ((int)threadIdx.x >> 6);
  if (seg >= nseg) return;
  const int lane = (int)threadIdx.x & 63;
  const int q = lane >> 4;
  const int cl = lane & 15;
  const int beg = off[seg], end = off[seg + 1];
  float a[8] = {};
  float den = 0.f;
  int i = beg;
  for (; i + 16 <= end; i += 16) {
    const int2 e0 = lst_es[i + q];
    const int2 e1 = lst_es[i + 4 + q];
    const int2 e2 = lst_es[i + 8 + q];
    const int2 e3 = lst_es[i + 12 + q];
    const uint4 r0 = *(const uint4*)(src + (size_t)e0.x * 128 + cl * 8);
    const uint4 r1 = *(const uint4*)(src + (size_t)e1.x * 128 + cl * 8);
    const uint4 r2 = *(const uint4*)(src + (size_t)e2.x * 128 + cl * 8);
    const uint4 r3 = *(const uint4*)(src + (size_t)e3.x * 128 + cl * 8);
    const float s0 = __int_as_float(e0.y), s1 = __int_as_float(e1.y);
    const float s2 = __int_as_float(e2.y), s3 = __int_as_float(e3.y);
    ACC8(r0, s0) ACC8(r1, s1) ACC8(r2, s2) ACC8(r3, s3)
    den += s0 + s1 + s2 + s3;
  }
  if (i + 8 <= end) {
    const int2 e0 = lst_es[i + q];
    const int2 e1 = lst_es[i + 4 + q];
    const uint4 r0 = *(const uint4*)(src + (size_t)e0.x * 128 + cl * 8);
    const uint4 r1 = *(const uint4*)(src + (size_t)e1.x * 128 + cl * 8);
    const float s0 = __int_as_float(e0.y), s1 = __int_as_float(e1.y);
    ACC8(r0, s0) ACC8(r1, s1)
    den += s0 + s1;
    i += 8;
  }
  if (i + 4 <= end) {
    const int2 e0 = lst_es[i + q];
    const uint4 r0 = *(const uint4*)(src + (size_t)e0.x * 128 + cl * 8);
    const float s0 = __int_as_float(e0.y);
    ACC8(r0, s0)
    den += s0;
    i += 4;
  }
  if (i + q < end) {
    const int2 e0 = lst_es[i + q];
    const uint4 r0 = *(const uint4*)(src + (size_t)e0.x * 128 + cl * 8);
    const float s0 = __int_as_float(e0.y);
    ACC8(r0, s0)
    den += s0;
  }
#pragma unroll
  for (int k = 0; k < 8; ++k) {
    a[k] += __shfl_xor(a[k], 16, 64);
    a[k] += __shfl_xor(a[k], 32, 64);
  }
  den += __shfl_xor(den, 16, 64);
  den += __shfl_xor(den, 32, 64);
  const float inv = (end > beg) ? 1.0f / den : 0.0f;
  if (q != 0) return;
  uint4 pk;
  pk.x = packbf(a[0] * inv, a[1] * inv); pk.y = packbf(a[2] * inv, a[3] * inv);
  pk.z = packbf(a[4] * inv, a[5] * inv); pk.w = packbf(a[6] * inv, a[7] * inv);
  *(uint4*)(dst + (size_t)seg * 128 + cl * 8) = pk;
}

extern "C" void kernel_launch(void* const* d_in, const int* in_sizes, int n_in,
                              void* d_out, int out_size, void* d_ws, size_t ws_size,
                              hipStream_t stream) {
  const float* X      = (const float*)d_in[0];
  const int*   pair_v = (const int*)d_in[1];
  const int*   pair_e = (const int*)d_in[2];
  const int*   src_v  = (const int*)d_in[3];
  const float* W      = (const float*)d_in[4];
  const float* bias   = (const float*)d_in[5];
  const float* wsrc   = (const float*)d_in[6];
  const float* wdst   = (const float*)d_in[7];

  const int N = in_sizes[0] / 128;
  const int P = in_sizes[1];
  const int M = M_EDGES;   // fixed by problem definition (pair_e in [0, 50000))
  const int CE = (M + CHUNK - 1) / CHUNK;   // <=256 for partscan
  const int CV = (N + CHUNK - 1) / CHUNK;   // <=256 for partscan

  char* w = (char*)d_ws;
  auto alloc = [&](size_t bytes) -> char* {
    char* p = w;
    w += (bytes + 255) & ~(size_t)255;
    return p;
  };
  // ---- zero-initialized region (one memset: counts only) ----
  char* zbase = w;
  int* cnt_e = (int*)alloc((size_t)M * 4);
  int* cnt_v = (int*)alloc((size_t)N * 4);
  const size_t zbytes = (size_t)(w - zbase);
  // ---- rest of workspace ----
  int*   cur_e     = (int*)alloc((size_t)M * 4);
  int*   cur_v     = (int*)alloc((size_t)N * 4);
  int*   part      = (int*)alloc((size_t)(CE + CV) * 4);
  int*   edge_off  = (int*)alloc((size_t)(M + 1) * 4);
  int*   vtx_off   = (int*)alloc((size_t)(N + 1) * 4);
  float* de_inv    = (float*)alloc((size_t)M * 4);
  float* dv_inv    = (float*)alloc((size_t)N * 4);
  float* dv_isqrt  = (float*)alloc((size_t)N * 4);
  float* svec      = (float*)alloc((size_t)N * 4);
  float* dvec      = (float*)alloc((size_t)N * 4);
  int*   edge_vtx  = (int*)alloc((size_t)P * 4);
  int2*  vtx_es    = (int2*)alloc((size_t)P * 8);
  u16*   bufN      = (u16*)alloc((size_t)N * 128 * 2);  // Hs -> Hs2 -> Xv1 (bf16)
  u16*   bufM      = (u16*)alloc((size_t)M * 128 * 2);  // Xe -> Xe1 -> Xe2 (bf16)

  hipMemsetAsync(zbase, 0, zbytes, stream);

  const int pb = (P + 255) / 256;
  count_kernel<<<pb, 256, 0, stream>>>(pair_e, pair_v, cnt_e, cnt_v, P);
  blocksum_kernel<<<CE + CV, 1024, 0, stream>>>(cnt_e, cnt_v, part, CE, M, N);
  partscan_kernel<<<1, 256, 0, stream>>>(part, CE, CV, edge_off, vtx_off, M, N);
  blockscan_kernel<<<CE + CV, 1024, 0, stream>>>(cnt_e, cnt_v, part, edge_off, vtx_off,
                                                 cur_e, cur_v, de_inv, dv_inv, dv_isqrt,
                                                 CE, M, N);
  gemm_kernel<<<(N + 31) / 32, 256, 0, stream>>>(X, W, bias, wsrc, wdst, dv_isqrt,
                                                 bufN, svec, dvec, N);
  fill_kernel<<<pb, 256, 0, stream>>>(pair_e, pair_v, src_v, cur_e, cur_v,
                                      edge_vtx, vtx_es, svec, dvec, P);

  const int gm = (M + 3) / 4;
  const int gn = (N + 3) / 4;
  // P1: Xe  = de_inv * sum Hs[v]          (dv_isqrt folded into Hs at GEMM)
  seg_pass_kernel<<<gm, 256, 0, stream>>>(bufN, bufM, edge_off, edge_vtx, 1, de_inv, M, 0);
  // P2: Hs2 = dv_isqrt * sum Xe[e]
  seg_pass_kernel<<<gn, 256, 0, stream>>>(bufM, bufN, vtx_off, (const int*)vtx_es, 2, dv_isqrt, N, 0);
  // P3: Xe1 = de_inv * sum Hs2[v]
  seg_pass_kernel<<<gm, 256, 0, stream>>>(bufN, bufM, edge_off, edge_vtx, 1, de_inv, M, 0);
  // P4: Xv1 = softmax-weighted sum of Xe1[e]
  attn_pass_kernel<<<gn, 256, 0, stream>>>(bufM, bufN, vtx_off, vtx_es, N);
  // P5: Xe2 = de_inv * sum Xv1[v]
  seg_pass_kernel<<<gm, 256, 0, stream>>>(bufN, bufM, edge_off, edge_vtx, 1, de_inv, M, 0);
  // P6: out = elu(dv_inv * sum Xe2[e])  -> fp32
  seg_pass_kernel<<<gn, 256, 0, stream>>>(bufM, d_out, vtx_off, (const int*)vtx_es, 2, dv_inv, N, 1);
}